// Round 10
// baseline (102.215 us; speedup 1.0000x reference)
//
#include <hip/hip_runtime.h>
#include <hip/hip_bf16.h>
#include <hip/hip_fp16.h>
#include <math.h>

// Problem: N=50000 nodes, E=800000 edges, D=G=128.
// out[v,:] = elu( sum_{e: dst(e)=v} softmax_e(leaky(pd[dst]+ps[src]+b)) * hv[src(e),:] )
// pd[v] = nf[v]·W_edge[0:D] (+ b_edge), ps[v] = nf[v]·W_edge[D:2D]
// hv = leaky_relu(nf @ W_node + b_node) via bf16 MFMA, stored as packed bf16 pairs.
// Edge ordering + full edge-softmax in the binned multisplit (place_kernel emits
// (src<<16)|f16(weight) per edge); aggregate is a pure weighted gather.
// Requires nN <= 65536 (src/dst packed in 16 bits) — holds for this problem.

#define BK_SHIFT 6
#define BK_CAP 2048
#define BIN_CHUNK 1024

using bf16x8 = __attribute__((ext_vector_type(8))) __bf16;
using f32x4 = __attribute__((ext_vector_type(4))) float;

static __device__ __forceinline__ unsigned pack_bf16(float x0, float x1) {
  unsigned u0 = (unsigned)__bfloat16_as_ushort(__float2bfloat16(x0));
  unsigned u1 = (unsigned)__bfloat16_as_ushort(__float2bfloat16(x1));
  return u0 | (u1 << 16);
}

// ---- one-time: convert Wn (128x128 f32) to bf16, pre-swizzled into B-fragment order.
// Also zeroes bcnt (replaces hipMemsetAsync — saves one in-graph fill dispatch).
__global__ void wconv_kernel(const float* __restrict__ Wn, ushort* __restrict__ wsw,
                             int* __restrict__ bcnt, int nB) {
  int i = blockIdx.x * 256 + threadIdx.x;  // 0..16383
  if (i < nB) bcnt[i] = 0;
  int j = i & 7, l = (i >> 3) & 63, ct = (i >> 9) & 7, kstep = i >> 12;
  int k = kstep * 32 + ((l >> 4) << 3) + j;
  int c = ct * 16 + (l & 15);
  wsw[i] = __bfloat16_as_ushort(__float2bfloat16(Wn[k * 128 + c]));
}

// ---------------- fused: hv MFMA GEMM (bf16) + per-node edge scalars ----------------
__global__ __launch_bounds__(256) void hv_mfma_kernel(
    const float* __restrict__ nf, const ushort* __restrict__ wsw,
    const float* __restrict__ bn, const float* __restrict__ We,
    const float* __restrict__ be, unsigned* __restrict__ hv2,
    float* __restrict__ pd, float* __restrict__ ps, int nN) {
  __shared__ unsigned Atile[64 * 64];  // 64 rows x 256B of bf16, XOR-swizzled 16B slots
  int row0 = blockIdx.x * 64;
  int t = threadIdx.x;
#pragma unroll
  for (int ss = 0; ss < 4; ++ss) {
    int s = t + ss * 256;
    int r = s >> 4, sl = s & 15;
    int gr = row0 + r;
    float4 f0 = make_float4(0.f, 0.f, 0.f, 0.f), f1 = f0;
    if (gr < nN) {
      const float4* p = reinterpret_cast<const float4*>(nf + (size_t)gr * 128 + sl * 8);
      f0 = p[0];
      f1 = p[1];
    }
    uint4 pk;
    pk.x = pack_bf16(f0.x, f0.y);
    pk.y = pack_bf16(f0.z, f0.w);
    pk.z = pack_bf16(f1.x, f1.y);
    pk.w = pack_bf16(f1.z, f1.w);
    int byte = r * 256 + ((sl * 16) ^ ((r & 7) << 4));  // T2 swizzle vs 16-way conflict
    *reinterpret_cast<uint4*>(reinterpret_cast<char*>(Atile) + byte) = pk;
  }
  __syncthreads();
  int lane = t & 63, w = t >> 6;
  // edge-projection scalars (fp32, reads nf from global -> L1/L2-hot after staging)
  float we0 = We[lane], we1 = We[64 + lane], we2 = We[128 + lane], we3 = We[192 + lane];
  float bev = be[0];
  for (int rr = 0; rr < 16; ++rr) {
    int gr = row0 + w * 16 + rr;
    if (gr >= nN) break;  // wave-uniform
    const float* rowp = nf + (size_t)gr * 128;
    float a0 = rowp[lane], a1 = rowp[64 + lane];
    float pdv = a0 * we0 + a1 * we1;
    float psv = a0 * we2 + a1 * we3;
#pragma unroll
    for (int o = 32; o; o >>= 1) {
      pdv += __shfl_xor(pdv, o);
      psv += __shfl_xor(psv, o);
    }
    if (lane == 0) {
      pd[gr] = pdv + bev;  // bias folded (added once per edge)
      ps[gr] = psv;
    }
  }
  // MFMA: wave w owns rows w*16..w*16+15, 8 col-tiles of 16, K=128 (4 ksteps)
  f32x4 acc[8];
#pragma unroll
  for (int c = 0; c < 8; ++c) acc[c] = (f32x4){0.f, 0.f, 0.f, 0.f};
  int rl = w * 16 + (lane & 15);
  const char* abase = reinterpret_cast<const char*>(Atile) + rl * 256;
  int ksel = (lane >> 4) * 16;
#pragma unroll
  for (int kstep = 0; kstep < 4; ++kstep) {
    int kb = kstep * 64 + ksel;
    bf16x8 afrag = *reinterpret_cast<const bf16x8*>(abase + (kb ^ ((rl & 7) << 4)));
#pragma unroll
    for (int ct = 0; ct < 8; ++ct) {
      bf16x8 bfrag = *reinterpret_cast<const bf16x8*>(wsw + ((size_t)((kstep * 8 + ct) * 64 + lane)) * 8);
      acc[ct] = __builtin_amdgcn_mfma_f32_16x16x32_bf16(afrag, bfrag, acc[ct], 0, 0, 0);
    }
  }
  // epilogue: D layout col=lane&15, row=(lane>>4)*4+reg; pack (c, c+1) via shfl
  int colbase = lane & 15;
  int rbase = row0 + w * 16 + ((lane >> 4) << 2);
#pragma unroll
  for (int ct = 0; ct < 8; ++ct) {
    int col = ct * 16 + colbase;
    float bb = bn[col];
#pragma unroll
    for (int r = 0; r < 4; ++r) {
      float x = acc[ct][r] + bb;
      x = x > 0.f ? x : 0.01f * x;
      float y = __shfl_xor(x, 1);
      int gr = rbase + r;
      if (!(lane & 1) && gr < nN)
        hv2[(size_t)gr * 64 + ct * 8 + (colbase >> 1)] = pack_bf16(x, y);
    }
  }
}

// ---------------- phase 1: multisplit bin by dst>>6 into fixed-CAP slots ----------------
// BIN_CHUNK=1024 -> 782 blocks (~3/CU) so the scatter has TLP to hide latency.
__global__ __launch_bounds__(256) void bin_kernel(
    const int* __restrict__ src, const int* __restrict__ dst,
    int* __restrict__ bcnt, unsigned* __restrict__ inter, int nE, int nB) {
  __shared__ int cnt[1024];  // supports nN <= 65536
  int t = threadIdx.x;
  for (int b = t; b < nB; b += 256) cnt[b] = 0;
  __syncthreads();
  int base = blockIdx.x * BIN_CHUNK;
  int dv[4];
#pragma unroll
  for (int k = 0; k < 4; ++k) {
    int e = base + t + k * 256;
    dv[k] = (e < nE) ? dst[e] : -1;
    if (dv[k] >= 0) atomicAdd(&cnt[dv[k] >> BK_SHIFT], 1);
  }
  __syncthreads();
  // reserve global bucket ranges; counter slot becomes this wg's running base
  for (int b = t; b < nB; b += 256) {
    int c = cnt[b];
    cnt[b] = c ? atomicAdd(&bcnt[b], c) : 0;
  }
  __syncthreads();
#pragma unroll
  for (int k = 0; k < 4; ++k) {
    int e = base + t + k * 256;
    if (e < nE) {
      int d = dv[k];
      int b = d >> BK_SHIFT;
      int pos = atomicAdd(&cnt[b], 1);
      if (pos < BK_CAP)
        inter[(size_t)b * BK_CAP + pos] = ((unsigned)src[e] << BK_SHIFT) | (unsigned)(d & 63);
    }
  }
}

// ---------------- phase 2: per-bucket sort + full edge softmax ----------------
// emits ssw[pos] = (src<<16) | f16bits(softmax weight), plus offs/deg per node.
// softmax reductions parallelized: thread t = (quarter q = t>>6, node = t&63),
// stride-4 partials combined in LDS (all 4 waves active).
__global__ __launch_bounds__(256) void place_kernel(
    const int* __restrict__ bcnt, const unsigned* __restrict__ inter,
    const float* __restrict__ pd, const float* __restrict__ ps,
    unsigned* __restrict__ ssw, int* __restrict__ offs, int* __restrict__ degv, int nN) {
  __shared__ unsigned recs[BK_CAP];
  __shared__ unsigned srt[BK_CAP];
  __shared__ float xsrt[BK_CAP];
  __shared__ int cnt[64], cur[64], segst[64];
  __shared__ float part[256];
  __shared__ float mx[64], rsum[64];
  int b = blockIdx.x;
  int t = threadIdx.x;
  int cntE = min(bcnt[b], BK_CAP);
  for (int i = t; i < cntE; i += 256) recs[i] = inter[(size_t)b * BK_CAP + i];
  if (t < 64) cnt[t] = 0;
  __syncthreads();
  for (int i = t; i < cntE; i += 256) atomicAdd(&cnt[recs[i] & 63], 1);
  __syncthreads();
  if (t < 64) {  // wave-0 exclusive scan of the 64 per-dst counts
    int c = cnt[t];
    int incl = c;
#pragma unroll
    for (int o = 1; o < 64; o <<= 1) {
      int x = __shfl_up(incl, o);
      if (t >= o) incl += x;
    }
    int excl = incl - c;
    cur[t] = excl;
    segst[t] = excl;
    int node = b * 64 + t;
    if (node < nN) {
      offs[node] = b * BK_CAP + excl;
      degv[node] = c;
    }
  }
  __syncthreads();
  // scatter into sorted order; compute leaky logit per edge (ps is L2-resident)
  for (int i = t; i < cntE; i += 256) {
    unsigned r = recs[i];
    int s = r >> BK_SHIFT, d = r & 63;
    float x = pd[b * 64 + d] + ps[s];
    x = x > 0.f ? x : 0.01f * x;
    int pos = atomicAdd(&cur[d], 1);
    srt[pos] = r;
    xsrt[pos] = x;
  }
  __syncthreads();
  {  // parallel per-node max: 4 threads per node, stride-4
    int node = t & 63, q = t >> 6;
    int st = segst[node], c = cnt[node];
    float m = -1e30f;
    for (int i = st + q; i < st + c; i += 4) m = fmaxf(m, xsrt[i]);
    part[t] = m;
  }
  __syncthreads();
  if (t < 64) mx[t] = fmaxf(fmaxf(part[t], part[64 + t]), fmaxf(part[128 + t], part[192 + t]));
  __syncthreads();
  {  // parallel per-node sum of exp
    int node = t & 63, q = t >> 6;
    int st = segst[node], c = cnt[node];
    float m = mx[node];
    float ss = 0.f;
    for (int i = st + q; i < st + c; i += 4) ss += __expf(xsrt[i] - m);
    part[t] = ss;
  }
  __syncthreads();
  if (t < 64) {
    float ss = part[t] + part[64 + t] + part[128 + t] + part[192 + t];
    rsum[t] = cnt[t] ? 1.f / ss : 0.f;
  }
  __syncthreads();
  for (int i = t; i < cntE; i += 256) {
    unsigned r = srt[i];
    int d = r & 63;
    float aw = __expf(xsrt[i] - mx[d]) * rsum[d];
    unsigned hw = (unsigned)__half_as_ushort(__float2half(aw));
    ssw[(size_t)b * BK_CAP + i] = ((r >> BK_SHIFT) << 16) | hw;
  }
}

// ---------------- aggregation: pure weighted gather, no shuffles ----------------
// one wave per destination node; lane handles feature pair (2*lane, 2*lane+1).
// 16 edges per unrolled step: 4 wave-uniform uint4 record loads + 16 row gathers
// in flight; OOB slots cndmask'd to rec=0 (weight 0, index 0 -> no NaN).
__global__ __launch_bounds__(256) void aggregate_kernel(
    const int* __restrict__ offs, const int* __restrict__ degv,
    const unsigned* __restrict__ ssw, const unsigned* __restrict__ hv2,
    float* __restrict__ out, int nN) {
  int v = blockIdx.x * 4 + (threadIdx.x >> 6);
  if (v >= nN) return;
  int lane = threadIdx.x & 63;
  int deg = degv[v];
  float2* out2 = reinterpret_cast<float2*>(out) + (size_t)v * 64 + lane;
  if (deg == 0) {  // no incoming edges: c = 0 -> elu(0) = 0
    *out2 = make_float2(0.f, 0.f);
    return;
  }
  int s0 = offs[v];
  float acc0 = 0.f, acc1 = 0.f;
  for (int i0 = 0; i0 < deg; i0 += 16) {
    uint4 r4[4];
#pragma unroll
    for (int q = 0; q < 4; ++q)
      r4[q] = *reinterpret_cast<const uint4*>(ssw + s0 + i0 + 4 * q);
    unsigned rec[16];
    rec[0] = r4[0].x; rec[1] = r4[0].y; rec[2] = r4[0].z; rec[3] = r4[0].w;
    rec[4] = r4[1].x; rec[5] = r4[1].y; rec[6] = r4[1].z; rec[7] = r4[1].w;
    rec[8] = r4[2].x; rec[9] = r4[2].y; rec[10] = r4[2].z; rec[11] = r4[2].w;
    rec[12] = r4[3].x; rec[13] = r4[3].y; rec[14] = r4[3].z; rec[15] = r4[3].w;
#pragma unroll
    for (int j = 0; j < 16; ++j) rec[j] = (i0 + j < deg) ? rec[j] : 0u;
    unsigned pk[16];
#pragma unroll
    for (int j = 0; j < 16; ++j) pk[j] = hv2[((rec[j] >> 16) << 6) + lane];  // 16 in flight
    float w[16];
#pragma unroll
    for (int j = 0; j < 16; ++j)  // VALU only — overlaps the gathers
      w[j] = __half2float(__ushort_as_half((unsigned short)(rec[j] & 0xffffu)));
#pragma unroll
    for (int j = 0; j < 16; ++j) {
      acc0 += w[j] * __uint_as_float(pk[j] << 16);
      acc1 += w[j] * __uint_as_float(pk[j] & 0xffff0000u);
    }
  }
  // elu: exp(x)-1 for x<0 (expm1 unnecessary: cancellation region error ~ulp(1))
  float e0 = acc0 > 0.f ? acc0 : __expf(acc0) - 1.f;
  float e1 = acc1 > 0.f ? acc1 : __expf(acc1) - 1.f;
  *out2 = make_float2(e0, e1);
}

extern "C" void kernel_launch(void* const* d_in, const int* in_sizes, int n_in,
                              void* d_out, int out_size, void* d_ws, size_t ws_size,
                              hipStream_t stream) {
  const float* nf = (const float*)d_in[0];
  const int* src = (const int*)d_in[1];
  const int* dst = (const int*)d_in[2];
  const float* We = (const float*)d_in[3];
  const float* be = (const float*)d_in[4];
  const float* Wn = (const float*)d_in[5];
  const float* bn = (const float*)d_in[6];
  float* out = (float*)d_out;
  int nN = in_sizes[0] / 128;
  int nE = in_sizes[1];
  int nB = (nN + 63) >> BK_SHIFT;

  // workspace carve (~26 MB), 16B-aligned chunks first
  char* wsp = (char*)d_ws;
  unsigned* hv2 = (unsigned*)wsp;   wsp += (size_t)nN * 64 * 4;
  unsigned* inter = (unsigned*)wsp; wsp += (size_t)nB * BK_CAP * 4;
  unsigned* ssw = (unsigned*)wsp;   wsp += (size_t)nB * BK_CAP * 4 + 64;  // +pad for uint4 overrun
  ushort* wsw = (ushort*)wsp;       wsp += 16384 * 2;
  float* pd = (float*)wsp;          wsp += (size_t)nN * 4;
  float* ps = (float*)wsp;          wsp += (size_t)nN * 4;
  int* offs = (int*)wsp;            wsp += (size_t)nN * 4;
  int* degv = (int*)wsp;            wsp += (size_t)nN * 4;
  int* bcnt = (int*)wsp;            wsp += (size_t)nB * 4;

  // wconv also zeroes bcnt (stream-ordered before bin_kernel).
  wconv_kernel<<<64, 256, 0, stream>>>(Wn, wsw, bcnt, nB);
  hv_mfma_kernel<<<(nN + 63) / 64, 256, 0, stream>>>(nf, wsw, bn, We, be, hv2, pd, ps, nN);
  bin_kernel<<<(nE + BIN_CHUNK - 1) / BIN_CHUNK, 256, 0, stream>>>(src, dst, bcnt, inter, nE, nB);
  place_kernel<<<nB, 256, 0, stream>>>(bcnt, inter, pd, ps, ssw, offs, degv, nN);
  aggregate_kernel<<<(nN + 3) / 4, 256, 0, stream>>>(offs, degv, ssw, hv2, out, nN);
}

// Round 11
// 89.364 us; speedup vs baseline: 1.1438x; 1.1438x over previous
//
#include <hip/hip_runtime.h>
#include <hip/hip_bf16.h>
#include <hip/hip_fp16.h>
#include <math.h>

// Problem: N=50000 nodes, E=800000 edges, D=G=128.
// out[v,:] = elu( sum_{e: dst(e)=v} softmax_e(leaky(pd[dst]+ps[src]+b)) * hv[src(e),:] )
// pd[v] = nf[v]·W_edge[0:D] (+ b_edge), ps[v] = nf[v]·W_edge[D:2D]
// hv = leaky_relu(nf @ W_node + b_node) via bf16 MFMA, stored as packed bf16 pairs.
// Edge ordering + full edge-softmax in the binned multisplit (place_kernel emits
// (src<<16)|f16(weight) per edge); aggregate is a pure weighted gather.
// Requires nN <= 65536 (src/dst packed in 16 bits) — holds for this problem.

#define BK_SHIFT 6
#define BK_CAP 2048
// BIN_CHUNK=4096 (196 blocks): fewer per-bucket reservation atomics; 1024 caused
// ~500-deep same-address atomic chains on bcnt and regressed 12 us (R10).
#define BIN_CHUNK 4096

using bf16x8 = __attribute__((ext_vector_type(8))) __bf16;
using f32x4 = __attribute__((ext_vector_type(4))) float;

static __device__ __forceinline__ unsigned pack_bf16(float x0, float x1) {
  unsigned u0 = (unsigned)__bfloat16_as_ushort(__float2bfloat16(x0));
  unsigned u1 = (unsigned)__bfloat16_as_ushort(__float2bfloat16(x1));
  return u0 | (u1 << 16);
}

// ---- one-time: convert Wn (128x128 f32) to bf16, pre-swizzled into B-fragment order.
// Also zeroes bcnt (replaces hipMemsetAsync — saves one in-graph fill dispatch).
__global__ void wconv_kernel(const float* __restrict__ Wn, ushort* __restrict__ wsw,
                             int* __restrict__ bcnt, int nB) {
  int i = blockIdx.x * 256 + threadIdx.x;  // 0..16383
  if (i < nB) bcnt[i] = 0;
  int j = i & 7, l = (i >> 3) & 63, ct = (i >> 9) & 7, kstep = i >> 12;
  int k = kstep * 32 + ((l >> 4) << 3) + j;
  int c = ct * 16 + (l & 15);
  wsw[i] = __bfloat16_as_ushort(__float2bfloat16(Wn[k * 128 + c]));
}

// ---------------- fused: hv MFMA GEMM (bf16) + per-node edge scalars ----------------
__global__ __launch_bounds__(256) void hv_mfma_kernel(
    const float* __restrict__ nf, const ushort* __restrict__ wsw,
    const float* __restrict__ bn, const float* __restrict__ We,
    const float* __restrict__ be, unsigned* __restrict__ hv2,
    float* __restrict__ pd, float* __restrict__ ps, int nN) {
  __shared__ unsigned Atile[64 * 64];  // 64 rows x 256B of bf16, XOR-swizzled 16B slots
  int row0 = blockIdx.x * 64;
  int t = threadIdx.x;
#pragma unroll
  for (int ss = 0; ss < 4; ++ss) {
    int s = t + ss * 256;
    int r = s >> 4, sl = s & 15;
    int gr = row0 + r;
    float4 f0 = make_float4(0.f, 0.f, 0.f, 0.f), f1 = f0;
    if (gr < nN) {
      const float4* p = reinterpret_cast<const float4*>(nf + (size_t)gr * 128 + sl * 8);
      f0 = p[0];
      f1 = p[1];
    }
    uint4 pk;
    pk.x = pack_bf16(f0.x, f0.y);
    pk.y = pack_bf16(f0.z, f0.w);
    pk.z = pack_bf16(f1.x, f1.y);
    pk.w = pack_bf16(f1.z, f1.w);
    int byte = r * 256 + ((sl * 16) ^ ((r & 7) << 4));  // T2 swizzle vs 16-way conflict
    *reinterpret_cast<uint4*>(reinterpret_cast<char*>(Atile) + byte) = pk;
  }
  __syncthreads();
  int lane = t & 63, w = t >> 6;
  // edge-projection scalars (fp32, reads nf from global -> L1/L2-hot after staging)
  float we0 = We[lane], we1 = We[64 + lane], we2 = We[128 + lane], we3 = We[192 + lane];
  float bev = be[0];
  for (int rr = 0; rr < 16; ++rr) {
    int gr = row0 + w * 16 + rr;
    if (gr >= nN) break;  // wave-uniform
    const float* rowp = nf + (size_t)gr * 128;
    float a0 = rowp[lane], a1 = rowp[64 + lane];
    float pdv = a0 * we0 + a1 * we1;
    float psv = a0 * we2 + a1 * we3;
#pragma unroll
    for (int o = 32; o; o >>= 1) {
      pdv += __shfl_xor(pdv, o);
      psv += __shfl_xor(psv, o);
    }
    if (lane == 0) {
      pd[gr] = pdv + bev;  // bias folded (added once per edge)
      ps[gr] = psv;
    }
  }
  // MFMA: wave w owns rows w*16..w*16+15, 8 col-tiles of 16, K=128 (4 ksteps)
  f32x4 acc[8];
#pragma unroll
  for (int c = 0; c < 8; ++c) acc[c] = (f32x4){0.f, 0.f, 0.f, 0.f};
  int rl = w * 16 + (lane & 15);
  const char* abase = reinterpret_cast<const char*>(Atile) + rl * 256;
  int ksel = (lane >> 4) * 16;
#pragma unroll
  for (int kstep = 0; kstep < 4; ++kstep) {
    int kb = kstep * 64 + ksel;
    bf16x8 afrag = *reinterpret_cast<const bf16x8*>(abase + (kb ^ ((rl & 7) << 4)));
#pragma unroll
    for (int ct = 0; ct < 8; ++ct) {
      bf16x8 bfrag = *reinterpret_cast<const bf16x8*>(wsw + ((size_t)((kstep * 8 + ct) * 64 + lane)) * 8);
      acc[ct] = __builtin_amdgcn_mfma_f32_16x16x32_bf16(afrag, bfrag, acc[ct], 0, 0, 0);
    }
  }
  // epilogue: D layout col=lane&15, row=(lane>>4)*4+reg; pack (c, c+1) via shfl
  int colbase = lane & 15;
  int rbase = row0 + w * 16 + ((lane >> 4) << 2);
#pragma unroll
  for (int ct = 0; ct < 8; ++ct) {
    int col = ct * 16 + colbase;
    float bb = bn[col];
#pragma unroll
    for (int r = 0; r < 4; ++r) {
      float x = acc[ct][r] + bb;
      x = x > 0.f ? x : 0.01f * x;
      float y = __shfl_xor(x, 1);
      int gr = rbase + r;
      if (!(lane & 1) && gr < nN)
        hv2[(size_t)gr * 64 + ct * 8 + (colbase >> 1)] = pack_bf16(x, y);
    }
  }
}

// ---------------- phase 1: multisplit bin by dst>>6 into fixed-CAP slots ----------------
__global__ __launch_bounds__(256) void bin_kernel(
    const int* __restrict__ src, const int* __restrict__ dst,
    int* __restrict__ bcnt, unsigned* __restrict__ inter, int nE, int nB) {
  __shared__ int cnt[1024];  // supports nN <= 65536
  int t = threadIdx.x;
  for (int b = t; b < nB; b += 256) cnt[b] = 0;
  __syncthreads();
  int base = blockIdx.x * BIN_CHUNK;
  int dv[16];
#pragma unroll
  for (int k = 0; k < 16; ++k) {
    int e = base + t + k * 256;
    dv[k] = (e < nE) ? dst[e] : -1;
    if (dv[k] >= 0) atomicAdd(&cnt[dv[k] >> BK_SHIFT], 1);
  }
  __syncthreads();
  // reserve global bucket ranges; counter slot becomes this wg's running base
  for (int b = t; b < nB; b += 256) {
    int c = cnt[b];
    cnt[b] = c ? atomicAdd(&bcnt[b], c) : 0;
  }
  __syncthreads();
#pragma unroll
  for (int k = 0; k < 16; ++k) {
    int e = base + t + k * 256;
    if (e < nE) {
      int d = dv[k];
      int b = d >> BK_SHIFT;
      int pos = atomicAdd(&cnt[b], 1);
      if (pos < BK_CAP)
        inter[(size_t)b * BK_CAP + pos] = ((unsigned)src[e] << BK_SHIFT) | (unsigned)(d & 63);
    }
  }
}

// ---------------- phase 2: per-bucket sort + full edge softmax ----------------
// emits ssw[pos] = (src<<16) | f16bits(softmax weight), plus offs/deg per node.
// softmax reductions parallelized: thread t = (quarter q = t>>6, node = t&63),
// stride-4 partials combined in LDS (all 4 waves active).
__global__ __launch_bounds__(256) void place_kernel(
    const int* __restrict__ bcnt, const unsigned* __restrict__ inter,
    const float* __restrict__ pd, const float* __restrict__ ps,
    unsigned* __restrict__ ssw, int* __restrict__ offs, int* __restrict__ degv, int nN) {
  __shared__ unsigned recs[BK_CAP];
  __shared__ unsigned srt[BK_CAP];
  __shared__ float xsrt[BK_CAP];
  __shared__ int cnt[64], cur[64], segst[64];
  __shared__ float part[256];
  __shared__ float mx[64], rsum[64];
  int b = blockIdx.x;
  int t = threadIdx.x;
  int cntE = min(bcnt[b], BK_CAP);
  for (int i = t; i < cntE; i += 256) recs[i] = inter[(size_t)b * BK_CAP + i];
  if (t < 64) cnt[t] = 0;
  __syncthreads();
  for (int i = t; i < cntE; i += 256) atomicAdd(&cnt[recs[i] & 63], 1);
  __syncthreads();
  if (t < 64) {  // wave-0 exclusive scan of the 64 per-dst counts
    int c = cnt[t];
    int incl = c;
#pragma unroll
    for (int o = 1; o < 64; o <<= 1) {
      int x = __shfl_up(incl, o);
      if (t >= o) incl += x;
    }
    int excl = incl - c;
    cur[t] = excl;
    segst[t] = excl;
    int node = b * 64 + t;
    if (node < nN) {
      offs[node] = b * BK_CAP + excl;
      degv[node] = c;
    }
  }
  __syncthreads();
  // scatter into sorted order; compute leaky logit per edge (ps is L2-resident)
  for (int i = t; i < cntE; i += 256) {
    unsigned r = recs[i];
    int s = r >> BK_SHIFT, d = r & 63;
    float x = pd[b * 64 + d] + ps[s];
    x = x > 0.f ? x : 0.01f * x;
    int pos = atomicAdd(&cur[d], 1);
    srt[pos] = r;
    xsrt[pos] = x;
  }
  __syncthreads();
  {  // parallel per-node max: 4 threads per node, stride-4
    int node = t & 63, q = t >> 6;
    int st = segst[node], c = cnt[node];
    float m = -1e30f;
    for (int i = st + q; i < st + c; i += 4) m = fmaxf(m, xsrt[i]);
    part[t] = m;
  }
  __syncthreads();
  if (t < 64) mx[t] = fmaxf(fmaxf(part[t], part[64 + t]), fmaxf(part[128 + t], part[192 + t]));
  __syncthreads();
  {  // parallel per-node sum of exp
    int node = t & 63, q = t >> 6;
    int st = segst[node], c = cnt[node];
    float m = mx[node];
    float ss = 0.f;
    for (int i = st + q; i < st + c; i += 4) ss += __expf(xsrt[i] - m);
    part[t] = ss;
  }
  __syncthreads();
  if (t < 64) {
    float ss = part[t] + part[64 + t] + part[128 + t] + part[192 + t];
    rsum[t] = cnt[t] ? 1.f / ss : 0.f;
  }
  __syncthreads();
  for (int i = t; i < cntE; i += 256) {
    unsigned r = srt[i];
    int d = r & 63;
    float aw = __expf(xsrt[i] - mx[d]) * rsum[d];
    unsigned hw = (unsigned)__half_as_ushort(__float2half(aw));
    ssw[(size_t)b * BK_CAP + i] = ((r >> BK_SHIFT) << 16) | hw;
  }
}

// ---------------- aggregation: pure weighted gather, no shuffles ----------------
// one wave per destination node; lane handles feature pair (2*lane, 2*lane+1).
// 16 edges per unrolled step: 4 wave-uniform uint4 record loads + 16 row gathers
// in flight; OOB slots cndmask'd to rec=0 (weight 0, index 0 -> no NaN).
__global__ __launch_bounds__(256) void aggregate_kernel(
    const int* __restrict__ offs, const int* __restrict__ degv,
    const unsigned* __restrict__ ssw, const unsigned* __restrict__ hv2,
    float* __restrict__ out, int nN) {
  int v = blockIdx.x * 4 + (threadIdx.x >> 6);
  if (v >= nN) return;
  int lane = threadIdx.x & 63;
  int deg = degv[v];
  float2* out2 = reinterpret_cast<float2*>(out) + (size_t)v * 64 + lane;
  if (deg == 0) {  // no incoming edges: c = 0 -> elu(0) = 0
    *out2 = make_float2(0.f, 0.f);
    return;
  }
  int s0 = offs[v];
  float acc0 = 0.f, acc1 = 0.f;
  for (int i0 = 0; i0 < deg; i0 += 16) {
    uint4 r4[4];
#pragma unroll
    for (int q = 0; q < 4; ++q)
      r4[q] = *reinterpret_cast<const uint4*>(ssw + s0 + i0 + 4 * q);
    unsigned rec[16];
    rec[0] = r4[0].x; rec[1] = r4[0].y; rec[2] = r4[0].z; rec[3] = r4[0].w;
    rec[4] = r4[1].x; rec[5] = r4[1].y; rec[6] = r4[1].z; rec[7] = r4[1].w;
    rec[8] = r4[2].x; rec[9] = r4[2].y; rec[10] = r4[2].z; rec[11] = r4[2].w;
    rec[12] = r4[3].x; rec[13] = r4[3].y; rec[14] = r4[3].z; rec[15] = r4[3].w;
#pragma unroll
    for (int j = 0; j < 16; ++j) rec[j] = (i0 + j < deg) ? rec[j] : 0u;
    unsigned pk[16];
#pragma unroll
    for (int j = 0; j < 16; ++j) pk[j] = hv2[((rec[j] >> 16) << 6) + lane];  // 16 in flight
    float w[16];
#pragma unroll
    for (int j = 0; j < 16; ++j)  // VALU only — overlaps the gathers
      w[j] = __half2float(__ushort_as_half((unsigned short)(rec[j] & 0xffffu)));
#pragma unroll
    for (int j = 0; j < 16; ++j) {
      acc0 += w[j] * __uint_as_float(pk[j] << 16);
      acc1 += w[j] * __uint_as_float(pk[j] & 0xffff0000u);
    }
  }
  // elu: exp(x)-1 for x<0 (expm1 unnecessary: cancellation region error ~ulp(1))
  float e0 = acc0 > 0.f ? acc0 : __expf(acc0) - 1.f;
  float e1 = acc1 > 0.f ? acc1 : __expf(acc1) - 1.f;
  *out2 = make_float2(e0, e1);
}

extern "C" void kernel_launch(void* const* d_in, const int* in_sizes, int n_in,
                              void* d_out, int out_size, void* d_ws, size_t ws_size,
                              hipStream_t stream) {
  const float* nf = (const float*)d_in[0];
  const int* src = (const int*)d_in[1];
  const int* dst = (const int*)d_in[2];
  const float* We = (const float*)d_in[3];
  const float* be = (const float*)d_in[4];
  const float* Wn = (const float*)d_in[5];
  const float* bn = (const float*)d_in[6];
  float* out = (float*)d_out;
  int nN = in_sizes[0] / 128;
  int nE = in_sizes[1];
  int nB = (nN + 63) >> BK_SHIFT;

  // workspace carve (~26 MB), 16B-aligned chunks first
  char* wsp = (char*)d_ws;
  unsigned* hv2 = (unsigned*)wsp;   wsp += (size_t)nN * 64 * 4;
  unsigned* inter = (unsigned*)wsp; wsp += (size_t)nB * BK_CAP * 4;
  unsigned* ssw = (unsigned*)wsp;   wsp += (size_t)nB * BK_CAP * 4 + 64;  // +pad for uint4 overrun
  ushort* wsw = (ushort*)wsp;       wsp += 16384 * 2;
  float* pd = (float*)wsp;          wsp += (size_t)nN * 4;
  float* ps = (float*)wsp;          wsp += (size_t)nN * 4;
  int* offs = (int*)wsp;            wsp += (size_t)nN * 4;
  int* degv = (int*)wsp;            wsp += (size_t)nN * 4;
  int* bcnt = (int*)wsp;            wsp += (size_t)nB * 4;

  // wconv also zeroes bcnt (stream-ordered before bin_kernel).
  wconv_kernel<<<64, 256, 0, stream>>>(Wn, wsw, bcnt, nB);
  hv_mfma_kernel<<<(nN + 63) / 64, 256, 0, stream>>>(nf, wsw, bn, We, be, hv2, pd, ps, nN);
  bin_kernel<<<(nE + BIN_CHUNK - 1) / BIN_CHUNK, 256, 0, stream>>>(src, dst, bcnt, inter, nE, nB);
  place_kernel<<<nB, 256, 0, stream>>>(bcnt, inter, pd, ps, ssw, offs, degv, nN);
  aggregate_kernel<<<(nN + 3) / 4, 256, 0, stream>>>(offs, degv, ssw, hv2, out, nN);
}

// Round 12
// 76.286 us; speedup vs baseline: 1.3399x; 1.1714x over previous
//
#include <hip/hip_runtime.h>
#include <hip/hip_bf16.h>
#include <hip/hip_fp16.h>
#include <math.h>

// Problem: N=50000 nodes, E=800000 edges, D=G=128.
// out[v,:] = elu( sum_{e: dst(e)=v} softmax_e(leaky(pd[dst]+ps[src]+b)) * hv[src(e),:] )
// pd[v] = nf[v]·W_edge[0:D] (+ b_edge), ps[v] = nf[v]·W_edge[D:2D]
// hv = leaky_relu(nf @ W_node + b_node) via bf16 MFMA, stored as packed bf16 pairs.
// Edge ordering + full edge-softmax in the binned multisplit; aggregate is a pure
// weighted gather. hv-GEMM and edge-binning are INDEPENDENT -> fused into one
// kernel (block-range dispatch) so the latency-bound binning overlaps the MFMA.
// Requires nN <= 65536 (src/dst packed in 16 bits) — holds for this problem.

#define BK_SHIFT 6
#define BK_CAP 2048
// BIN_CHUNK=4096 (196 blocks): fewer per-bucket reservation atomics; 1024 caused
// ~500-deep same-address atomic chains on bcnt and regressed 12 us (R10).
#define BIN_CHUNK 4096

using bf16x8 = __attribute__((ext_vector_type(8))) __bf16;
using f32x4 = __attribute__((ext_vector_type(4))) float;

static __device__ __forceinline__ unsigned pack_bf16(float x0, float x1) {
  unsigned u0 = (unsigned)__bfloat16_as_ushort(__float2bfloat16(x0));
  unsigned u1 = (unsigned)__bfloat16_as_ushort(__float2bfloat16(x1));
  return u0 | (u1 << 16);
}

// ---- one-time: convert Wn (128x128 f32) to bf16, pre-swizzled into B-fragment order.
// Also zeroes bcnt (replaces hipMemsetAsync — saves one in-graph fill dispatch).
__global__ void wconv_kernel(const float* __restrict__ Wn, ushort* __restrict__ wsw,
                             int* __restrict__ bcnt, int nB) {
  int i = blockIdx.x * 256 + threadIdx.x;  // 0..16383
  if (i < nB) bcnt[i] = 0;
  int j = i & 7, l = (i >> 3) & 63, ct = (i >> 9) & 7, kstep = i >> 12;
  int k = kstep * 32 + ((l >> 4) << 3) + j;
  int c = ct * 16 + (l & 15);
  wsw[i] = __bfloat16_as_ushort(__float2bfloat16(Wn[k * 128 + c]));
}

// -------- fused: [blocks 0..nBin) edge-binning  |  [nBin..) hv MFMA GEMM --------
// The two paths use disjoint pipes (VMEM/atomics vs MFMA/LDS) and overlap.
__global__ __launch_bounds__(256) void hv_bin_kernel(
    const float* __restrict__ nf, const ushort* __restrict__ wsw,
    const float* __restrict__ bn, const float* __restrict__ We,
    const float* __restrict__ be, unsigned* __restrict__ hv2,
    float* __restrict__ pd, float* __restrict__ ps, int nN,
    const int* __restrict__ src, const int* __restrict__ dst,
    int* __restrict__ bcnt, unsigned* __restrict__ inter, int nE, int nB, int nBin) {
  __shared__ unsigned shmem[64 * 64];  // 16KB: Atile (hv path) / cnt[1024] (bin path)
  int t = threadIdx.x;

  if ((int)blockIdx.x < nBin) {
    // ---------------- bin path: multisplit by dst>>6 into fixed-CAP slots ----------------
    int* cnt = (int*)shmem;
    for (int b = t; b < nB; b += 256) cnt[b] = 0;
    __syncthreads();
    int base = blockIdx.x * BIN_CHUNK;
    int dv[16];
#pragma unroll
    for (int k = 0; k < 16; ++k) {
      int e = base + t + k * 256;
      dv[k] = (e < nE) ? dst[e] : -1;
      if (dv[k] >= 0) atomicAdd(&cnt[dv[k] >> BK_SHIFT], 1);
    }
    __syncthreads();
    // reserve global bucket ranges; counter slot becomes this wg's running base
    for (int b = t; b < nB; b += 256) {
      int c = cnt[b];
      cnt[b] = c ? atomicAdd(&bcnt[b], c) : 0;
    }
    __syncthreads();
#pragma unroll
    for (int k = 0; k < 16; ++k) {
      int e = base + t + k * 256;
      if (e < nE) {
        int d = dv[k];
        int b = d >> BK_SHIFT;
        int pos = atomicAdd(&cnt[b], 1);
        if (pos < BK_CAP)
          inter[(size_t)b * BK_CAP + pos] = ((unsigned)src[e] << BK_SHIFT) | (unsigned)(d & 63);
      }
    }
    return;
  }

  // ---------------- hv path: MFMA GEMM + per-node edge scalars ----------------
  unsigned* Atile = shmem;  // 64 rows x 256B of bf16, XOR-swizzled 16B slots
  int row0 = ((int)blockIdx.x - nBin) * 64;
#pragma unroll
  for (int ss = 0; ss < 4; ++ss) {
    int s = t + ss * 256;
    int r = s >> 4, sl = s & 15;
    int gr = row0 + r;
    float4 f0 = make_float4(0.f, 0.f, 0.f, 0.f), f1 = f0;
    if (gr < nN) {
      const float4* p = reinterpret_cast<const float4*>(nf + (size_t)gr * 128 + sl * 8);
      f0 = p[0];
      f1 = p[1];
    }
    uint4 pk;
    pk.x = pack_bf16(f0.x, f0.y);
    pk.y = pack_bf16(f0.z, f0.w);
    pk.z = pack_bf16(f1.x, f1.y);
    pk.w = pack_bf16(f1.z, f1.w);
    int byte = r * 256 + ((sl * 16) ^ ((r & 7) << 4));  // T2 swizzle vs 16-way conflict
    *reinterpret_cast<uint4*>(reinterpret_cast<char*>(Atile) + byte) = pk;
  }
  __syncthreads();
  int lane = t & 63, w = t >> 6;
  // edge-projection scalars (fp32, reads nf from global -> L1/L2-hot after staging)
  float we0 = We[lane], we1 = We[64 + lane], we2 = We[128 + lane], we3 = We[192 + lane];
  float bev = be[0];
  for (int rr = 0; rr < 16; ++rr) {
    int gr = row0 + w * 16 + rr;
    if (gr >= nN) break;  // wave-uniform
    const float* rowp = nf + (size_t)gr * 128;
    float a0 = rowp[lane], a1 = rowp[64 + lane];
    float pdv = a0 * we0 + a1 * we1;
    float psv = a0 * we2 + a1 * we3;
#pragma unroll
    for (int o = 32; o; o >>= 1) {
      pdv += __shfl_xor(pdv, o);
      psv += __shfl_xor(psv, o);
    }
    if (lane == 0) {
      pd[gr] = pdv + bev;  // bias folded (added once per edge)
      ps[gr] = psv;
    }
  }
  // MFMA: wave w owns rows w*16..w*16+15, 8 col-tiles of 16, K=128 (4 ksteps)
  f32x4 acc[8];
#pragma unroll
  for (int c = 0; c < 8; ++c) acc[c] = (f32x4){0.f, 0.f, 0.f, 0.f};
  int rl = w * 16 + (lane & 15);
  const char* abase = reinterpret_cast<const char*>(Atile) + rl * 256;
  int ksel = (lane >> 4) * 16;
#pragma unroll
  for (int kstep = 0; kstep < 4; ++kstep) {
    int kb = kstep * 64 + ksel;
    bf16x8 afrag = *reinterpret_cast<const bf16x8*>(abase + (kb ^ ((rl & 7) << 4)));
#pragma unroll
    for (int ct = 0; ct < 8; ++ct) {
      bf16x8 bfrag = *reinterpret_cast<const bf16x8*>(wsw + ((size_t)((kstep * 8 + ct) * 64 + lane)) * 8);
      acc[ct] = __builtin_amdgcn_mfma_f32_16x16x32_bf16(afrag, bfrag, acc[ct], 0, 0, 0);
    }
  }
  // epilogue: D layout col=lane&15, row=(lane>>4)*4+reg; pack (c, c+1) via shfl
  int colbase = lane & 15;
  int rbase = row0 + w * 16 + ((lane >> 4) << 2);
#pragma unroll
  for (int ct = 0; ct < 8; ++ct) {
    int col = ct * 16 + colbase;
    float bb = bn[col];
#pragma unroll
    for (int r = 0; r < 4; ++r) {
      float x = acc[ct][r] + bb;
      x = x > 0.f ? x : 0.01f * x;
      float y = __shfl_xor(x, 1);
      int gr = rbase + r;
      if (!(lane & 1) && gr < nN)
        hv2[(size_t)gr * 64 + ct * 8 + (colbase >> 1)] = pack_bf16(x, y);
    }
  }
}

// ---------------- phase 2: per-bucket sort + full edge softmax ----------------
// emits ssw[pos] = (src<<16) | f16bits(softmax weight), plus offs/deg per node.
// softmax reductions parallelized: thread t = (quarter q = t>>6, node = t&63),
// stride-4 partials combined in LDS (all 4 waves active).
__global__ __launch_bounds__(256) void place_kernel(
    const int* __restrict__ bcnt, const unsigned* __restrict__ inter,
    const float* __restrict__ pd, const float* __restrict__ ps,
    unsigned* __restrict__ ssw, int* __restrict__ offs, int* __restrict__ degv, int nN) {
  __shared__ unsigned recs[BK_CAP];
  __shared__ unsigned srt[BK_CAP];
  __shared__ float xsrt[BK_CAP];
  __shared__ int cnt[64], cur[64], segst[64];
  __shared__ float part[256];
  __shared__ float mx[64], rsum[64];
  int b = blockIdx.x;
  int t = threadIdx.x;
  int cntE = min(bcnt[b], BK_CAP);
  for (int i = t; i < cntE; i += 256) recs[i] = inter[(size_t)b * BK_CAP + i];
  if (t < 64) cnt[t] = 0;
  __syncthreads();
  for (int i = t; i < cntE; i += 256) atomicAdd(&cnt[recs[i] & 63], 1);
  __syncthreads();
  if (t < 64) {  // wave-0 exclusive scan of the 64 per-dst counts
    int c = cnt[t];
    int incl = c;
#pragma unroll
    for (int o = 1; o < 64; o <<= 1) {
      int x = __shfl_up(incl, o);
      if (t >= o) incl += x;
    }
    int excl = incl - c;
    cur[t] = excl;
    segst[t] = excl;
    int node = b * 64 + t;
    if (node < nN) {
      offs[node] = b * BK_CAP + excl;
      degv[node] = c;
    }
  }
  __syncthreads();
  // scatter into sorted order; compute leaky logit per edge (ps is L2-resident)
  for (int i = t; i < cntE; i += 256) {
    unsigned r = recs[i];
    int s = r >> BK_SHIFT, d = r & 63;
    float x = pd[b * 64 + d] + ps[s];
    x = x > 0.f ? x : 0.01f * x;
    int pos = atomicAdd(&cur[d], 1);
    srt[pos] = r;
    xsrt[pos] = x;
  }
  __syncthreads();
  {  // parallel per-node max: 4 threads per node, stride-4
    int node = t & 63, q = t >> 6;
    int st = segst[node], c = cnt[node];
    float m = -1e30f;
    for (int i = st + q; i < st + c; i += 4) m = fmaxf(m, xsrt[i]);
    part[t] = m;
  }
  __syncthreads();
  if (t < 64) mx[t] = fmaxf(fmaxf(part[t], part[64 + t]), fmaxf(part[128 + t], part[192 + t]));
  __syncthreads();
  {  // parallel per-node sum of exp
    int node = t & 63, q = t >> 6;
    int st = segst[node], c = cnt[node];
    float m = mx[node];
    float ss = 0.f;
    for (int i = st + q; i < st + c; i += 4) ss += __expf(xsrt[i] - m);
    part[t] = ss;
  }
  __syncthreads();
  if (t < 64) {
    float ss = part[t] + part[64 + t] + part[128 + t] + part[192 + t];
    rsum[t] = cnt[t] ? 1.f / ss : 0.f;
  }
  __syncthreads();
  for (int i = t; i < cntE; i += 256) {
    unsigned r = srt[i];
    int d = r & 63;
    float aw = __expf(xsrt[i] - mx[d]) * rsum[d];
    unsigned hw = (unsigned)__half_as_ushort(__float2half(aw));
    ssw[(size_t)b * BK_CAP + i] = ((r >> BK_SHIFT) << 16) | hw;
  }
}

// ---------------- aggregation: pure weighted gather, no shuffles ----------------
// one wave per destination node; lane handles feature pair (2*lane, 2*lane+1).
// 16 edges per unrolled step: 4 wave-uniform uint4 record loads + 16 row gathers
// in flight; OOB slots cndmask'd to rec=0 (weight 0, index 0 -> no NaN).
__global__ __launch_bounds__(256) void aggregate_kernel(
    const int* __restrict__ offs, const int* __restrict__ degv,
    const unsigned* __restrict__ ssw, const unsigned* __restrict__ hv2,
    float* __restrict__ out, int nN) {
  int v = blockIdx.x * 4 + (threadIdx.x >> 6);
  if (v >= nN) return;
  int lane = threadIdx.x & 63;
  int deg = degv[v];
  float2* out2 = reinterpret_cast<float2*>(out) + (size_t)v * 64 + lane;
  if (deg == 0) {  // no incoming edges: c = 0 -> elu(0) = 0
    *out2 = make_float2(0.f, 0.f);
    return;
  }
  int s0 = offs[v];
  float acc0 = 0.f, acc1 = 0.f;
  for (int i0 = 0; i0 < deg; i0 += 16) {
    uint4 r4[4];
#pragma unroll
    for (int q = 0; q < 4; ++q)
      r4[q] = *reinterpret_cast<const uint4*>(ssw + s0 + i0 + 4 * q);
    unsigned rec[16];
    rec[0] = r4[0].x; rec[1] = r4[0].y; rec[2] = r4[0].z; rec[3] = r4[0].w;
    rec[4] = r4[1].x; rec[5] = r4[1].y; rec[6] = r4[1].z; rec[7] = r4[1].w;
    rec[8] = r4[2].x; rec[9] = r4[2].y; rec[10] = r4[2].z; rec[11] = r4[2].w;
    rec[12] = r4[3].x; rec[13] = r4[3].y; rec[14] = r4[3].z; rec[15] = r4[3].w;
#pragma unroll
    for (int j = 0; j < 16; ++j) rec[j] = (i0 + j < deg) ? rec[j] : 0u;
    unsigned pk[16];
#pragma unroll
    for (int j = 0; j < 16; ++j) pk[j] = hv2[((rec[j] >> 16) << 6) + lane];  // 16 in flight
    float w[16];
#pragma unroll
    for (int j = 0; j < 16; ++j)  // VALU only — overlaps the gathers
      w[j] = __half2float(__ushort_as_half((unsigned short)(rec[j] & 0xffffu)));
#pragma unroll
    for (int j = 0; j < 16; ++j) {
      acc0 += w[j] * __uint_as_float(pk[j] << 16);
      acc1 += w[j] * __uint_as_float(pk[j] & 0xffff0000u);
    }
  }
  // elu: exp(x)-1 for x<0 (expm1 unnecessary: cancellation region error ~ulp(1))
  float e0 = acc0 > 0.f ? acc0 : __expf(acc0) - 1.f;
  float e1 = acc1 > 0.f ? acc1 : __expf(acc1) - 1.f;
  *out2 = make_float2(e0, e1);
}

extern "C" void kernel_launch(void* const* d_in, const int* in_sizes, int n_in,
                              void* d_out, int out_size, void* d_ws, size_t ws_size,
                              hipStream_t stream) {
  const float* nf = (const float*)d_in[0];
  const int* src = (const int*)d_in[1];
  const int* dst = (const int*)d_in[2];
  const float* We = (const float*)d_in[3];
  const float* be = (const float*)d_in[4];
  const float* Wn = (const float*)d_in[5];
  const float* bn = (const float*)d_in[6];
  float* out = (float*)d_out;
  int nN = in_sizes[0] / 128;
  int nE = in_sizes[1];
  int nB = (nN + 63) >> BK_SHIFT;
  int nBin = (nE + BIN_CHUNK - 1) / BIN_CHUNK;
  int nHV = (nN + 63) / 64;

  // workspace carve (~26 MB), 16B-aligned chunks first
  char* wsp = (char*)d_ws;
  unsigned* hv2 = (unsigned*)wsp;   wsp += (size_t)nN * 64 * 4;
  unsigned* inter = (unsigned*)wsp; wsp += (size_t)nB * BK_CAP * 4;
  unsigned* ssw = (unsigned*)wsp;   wsp += (size_t)nB * BK_CAP * 4 + 64;  // +pad for uint4 overrun
  ushort* wsw = (ushort*)wsp;       wsp += 16384 * 2;
  float* pd = (float*)wsp;          wsp += (size_t)nN * 4;
  float* ps = (float*)wsp;          wsp += (size_t)nN * 4;
  int* offs = (int*)wsp;            wsp += (size_t)nN * 4;
  int* degv = (int*)wsp;            wsp += (size_t)nN * 4;
  int* bcnt = (int*)wsp;            wsp += (size_t)nB * 4;

  // wconv also zeroes bcnt (stream-ordered before the fused kernel's bin path).
  wconv_kernel<<<64, 256, 0, stream>>>(Wn, wsw, bcnt, nB);
  hv_bin_kernel<<<nBin + nHV, 256, 0, stream>>>(nf, wsw, bn, We, be, hv2, pd, ps, nN,
                                                src, dst, bcnt, inter, nE, nB, nBin);
  place_kernel<<<nB, 256, 0, stream>>>(bcnt, inter, pd, ps, ssw, offs, degv, nN);
  aggregate_kernel<<<(nN + 3) / 4, 256, 0, stream>>>(offs, degv, ssw, hv2, out, nN);
}